// Round 2
// baseline (17527.649 us; speedup 1.0000x reference)
//
#include <hip/hip_runtime.h>
#include <cstdint>
#include <cstddef>

// Problem constants
#define T_STEPS 8192
#define IN_DIM  1024
#define HID     1024
#define OUT_DIM 1024
#define G4      4096   // 4*HID

// Recurrence geometry: 256 blocks x 256 threads (4 waves), 1 block/CU.
// R10 (this round): the step is latency-chain bound on publish -> L3 ->
// poll-detect. Two timing changes, protocol unchanged:
//  - EARLY POLL ISSUE: the first poll-load set for tag t+1 is issued
//    immediately after the publish (pinned with sched_barrier), BEFORE the
//    shadow work (y-dot, x-partials). The shadow (~300cy) now hides under
//    the poll load's flight time instead of delaying it.
//  - STAGGERED SPIN: two poll-load sets A/B kept in flight alternately;
//    each check waits only for the older set while the newer is in flight,
//    halving the detect quantization from ~L to ~L/2.
#define NBLK 256
#define TPB  256
#define UPB  4    // units per block (1 per wave)

typedef __attribute__((ext_vector_type(4))) float f32x4;

#define PLOAD(p) __hip_atomic_load((p), __ATOMIC_RELAXED, __HIP_MEMORY_SCOPE_AGENT)

__device__ __forceinline__ float sigf(float x) {
  return 1.0f / (1.0f + __expf(-x));
}

template<int CTRL>
__device__ __forceinline__ float dpp_add(float v) {
  int p = __builtin_amdgcn_update_dpp(0, __float_as_int(v), CTRL, 0xf, 0xf, true);
  return v + __int_as_float(p);
}

// Full 64-lane sum, all-VALU (DPP). Result valid in LANE 63 only.
__device__ __forceinline__ float wave_sum63(float v) {
  v = dpp_add<0xB1>(v);    // quad_perm [1,0,3,2]
  v = dpp_add<0x4E>(v);    // quad_perm [2,3,0,1]
  v = dpp_add<0x141>(v);   // row_half_mirror
  v = dpp_add<0x140>(v);   // row_mirror
  v = dpp_add<0x142>(v);   // row_bcast15
  v = dpp_add<0x143>(v);   // row_bcast31
  return v;
}

// ---------------------------------------------------------------------------
// Fused persistent LSTM: tagged dataflow (no device barrier), LDS-resident
// W_h and W_x, reg-resident out_w row. hbuf: [2][1024] u64 {lo=tag, hi=h}.
// Iteration t (t = 0..T inclusive):
//   A) issue x_{t+1} prefetch (flight covers the spin + gates)
//   B) staggered spin on my 256-chunk of slot t&1 for tag t (sets A/B)
//   C) deposit into lh[t&1]; raw barrier (lgkmcnt only; vmem in flight)
//   D) hv = full h_{t-1} from LDS
//   E) [t<T] gates: chain init = pp[] (x-partials), 64 FMA vs reg-pinned
//      W_h, DPP reduce -> lane 63: acts, c, h, publish tag t+1
//   -- sched_barrier: nothing below may delay the publish --
//   P) [t<T] EARLY ISSUE of poll set A for tag t+1 (pinned)
//   F) [t>0] y_{t-1} = out_w[u].hv (+DPP reduce), lane 63 stores out[t-1]
//   G) [t+1<T] pp[] = per-lane partials of W_x . x_{t+1}
// Skew safety (unchanged from R9): every wave consumes the FULL h each step
// via its chunk + barrier; tag t+2 publish implies all waves passed poll
// t+1, so depth-2 slots never skip a tag. Publish stores are never
// vmcnt-drained in-loop; pollers enforce visibility.
// ---------------------------------------------------------------------------
__global__ __launch_bounds__(TPB, 1) void lstm_fused(
    const float* __restrict__ Ww,                 // [4096, 2048]
    const float* __restrict__ xg,                 // [T, 1024]
    const float* __restrict__ owm,                // [1024, 1024]
    const float* __restrict__ wb,                 // [4096]
    const float* __restrict__ obv,                // [1024]
    unsigned long long* __restrict__ hbuf,        // [2][1024] tagged
    float* __restrict__ out)                      // [T, 1024]
{
  __shared__ float whlds[16][HID];  // 64 KB: W_h rows m = ul*4+g
  __shared__ float wxlds[16][HID];  // 64 KB: W_x rows, same layout
  __shared__ float lh[2][HID];      // 8 KB: staged h, double-buffered

  const int tid = threadIdx.x;
  const int lane = tid & 63;
  const int wslot = tid >> 6;                 // 0..3 = unit-in-block
  const int u = blockIdx.x * UPB + wslot;     // this wave's hidden unit

  // Stage W_h and W_x rows for this block (float4, coalesced).
  {
    const float4* __restrict__ Ww4 = (const float4*)Ww;  // row stride 512 f4
    float4* wh4 = (float4*)&whlds[0][0];
    float4* wx4 = (float4*)&wxlds[0][0];
    for (int i = tid; i < 16 * 256; i += TPB) {
      const int m = i >> 8;            // 0..15
      const int e4 = i & 255;          // float4 index within row
      const int gg = m & 3;
      const int ul = m >> 2;
      const size_t row = (size_t)(gg * HID + blockIdx.x * UPB + ul) * 512;
      wh4[i] = Ww4[row + (IN_DIM / 4) + e4];   // recurrent half
      wx4[i] = Ww4[row + e4];                  // input half
    }
  }
  __syncthreads();

  const f32x4* wl4 = (const f32x4*)&whlds[wslot * 4][0];
  const f32x4* wxl = (const f32x4*)&wxlds[wslot * 4][0];

  // Hoist W_h fragments into registers for the whole loop (loop-invariant).
  f32x4 W[16];
#pragma unroll
  for (int r = 0; r < 4; ++r)
#pragma unroll
    for (int k = 0; k < 4; ++k)
      W[r * 4 + k] = wl4[r * 256 + k * 64 + lane];
#pragma unroll
  for (int i = 0; i < 16; ++i) asm volatile("" : "+v"(W[i]));

  // out_w row for this unit, pinned (16 VGPRs).
  f32x4 O[4];
  {
    const f32x4* ow4 = (const f32x4*)(owm + (size_t)u * HID);
#pragma unroll
    for (int k = 0; k < 4; ++k) O[k] = ow4[k * 64 + lane];
#pragma unroll
    for (int k = 0; k < 4; ++k) asm volatile("" : "+v"(O[k]));
  }

  const float bi = wb[u],           bf = wb[HID + u];
  const float bg = wb[2 * HID + u], bo = wb[3 * HID + u];
  const float oby = obv[u];

  // Prologue: x-partials for step 0.
  float pp[4];
  {
    const f32x4* xt4 = (const f32x4*)xg;
    f32x4 x0[4];
#pragma unroll
    for (int k = 0; k < 4; ++k) x0[k] = xt4[k * 64 + lane];
#pragma unroll
    for (int r = 0; r < 4; ++r) {
      float s = 0.0f;
#pragma unroll
      for (int k = 0; k < 4; ++k) {
        const f32x4 wx = wxl[r * 256 + k * 64 + lane];
        s = fmaf(wx.x, x0[k].x, s); s = fmaf(wx.y, x0[k].y, s);
        s = fmaf(wx.z, x0[k].z, s); s = fmaf(wx.w, x0[k].w, s);
      }
      pp[r] = s;
    }
  }

  float c = 0.0f;

  // Pre-issue poll set A for t=0 (slot 0; tags are 0 from the memset).
  unsigned long long A0, A1, A2, A3;
  {
    const unsigned long long* hs = hbuf + wslot * 256;
    A0 = PLOAD(hs + lane);       A1 = PLOAD(hs + 64 + lane);
    A2 = PLOAD(hs + 128 + lane); A3 = PLOAD(hs + 192 + lane);
  }

  for (int t = 0; t <= T_STEPS; ++t) {
    // A) x_{t+1} prefetch: flight covers the spin + gate compute.
    f32x4 xn[4];
    const bool havex = (t + 1 < T_STEPS);
    if (havex) {
      const f32x4* xt4 = (const f32x4*)(xg + (size_t)(t + 1) * IN_DIM);
#pragma unroll
      for (int k = 0; k < 4; ++k) xn[k] = xt4[k * 64 + lane];
    }
    __builtin_amdgcn_sched_barrier(0);

    // B) staggered spin: check A (in flight since last publish), keep B
    // in flight during each check -> detect granularity ~L/2.
    const unsigned long long* hs = hbuf + (size_t)(t & 1) * HID + wslot * 256;
    const unsigned want = (unsigned)t;
    unsigned long long p0, p1, p2, p3;
    for (;;) {
      unsigned long long b0 = PLOAD(hs + lane);
      unsigned long long b1 = PLOAD(hs + 64 + lane);
      unsigned long long b2 = PLOAD(hs + 128 + lane);
      unsigned long long b3 = PLOAD(hs + 192 + lane);
      bool ok = ((unsigned)A0 == want) & ((unsigned)A1 == want) &
                ((unsigned)A2 == want) & ((unsigned)A3 == want);
      if (__all((int)ok)) { p0 = A0; p1 = A1; p2 = A2; p3 = A3; break; }
      A0 = PLOAD(hs + lane);
      A1 = PLOAD(hs + 64 + lane);
      A2 = PLOAD(hs + 128 + lane);
      A3 = PLOAD(hs + 192 + lane);
      ok = ((unsigned)b0 == want) & ((unsigned)b1 == want) &
           ((unsigned)b2 == want) & ((unsigned)b3 == want);
      if (__all((int)ok)) { p0 = b0; p1 = b1; p2 = b2; p3 = b3; break; }
    }
    {
      float* dst = &lh[t & 1][wslot * 256];
      dst[lane]       = __uint_as_float((unsigned)(p0 >> 32));
      dst[64 + lane]  = __uint_as_float((unsigned)(p1 >> 32));
      dst[128 + lane] = __uint_as_float((unsigned)(p2 >> 32));
      dst[192 + lane] = __uint_as_float((unsigned)(p3 >> 32));
    }

    // C) raw barrier: drain LDS ops only; global loads/stores stay in flight
    asm volatile("s_waitcnt lgkmcnt(0)\n\ts_barrier" ::: "memory");

    // D) full h_{t-1} from LDS
    const f32x4* lhp = (const f32x4*)&lh[t & 1][0];
    f32x4 hv[4];
#pragma unroll
    for (int k = 0; k < 4; ++k) hv[k] = lhp[k * 64 + lane];

    // E) gates -> h_t -> publish (critical path; lane 63 is the publisher)
    if (t < T_STEPS) {
      float a[4];
#pragma unroll
      for (int r = 0; r < 4; ++r) {
        float s = pp[r];   // x-partial initializes the chain (summed by tree)
#pragma unroll
        for (int k = 0; k < 4; ++k) {
          s = fmaf(W[r*4+k].x, hv[k].x, s); s = fmaf(W[r*4+k].y, hv[k].y, s);
          s = fmaf(W[r*4+k].z, hv[k].z, s); s = fmaf(W[r*4+k].w, hv[k].w, s);
        }
        a[r] = wave_sum63(s);
      }
      // Only lane 63 holds real sums; other lanes compute garbage harmlessly.
      const float gi = a[0] + bi, gf = a[1] + bf, gc = a[2] + bg, go = a[3] + bo;
      const float si = sigf(gi), sf = sigf(gf), so = sigf(go);
      const float tg = fmaf(2.0f, sigf(2.0f * gc), -1.0f);   // tanh
      c = fmaf(sf, c, si * tg);
      const float h = so * fmaf(2.0f, sigf(2.0f * c), -1.0f);
      if (lane == 63) {
        const unsigned long long pk =
            ((unsigned long long)__float_as_uint(h) << 32) | (unsigned)(t + 1);
        __hip_atomic_store(hbuf + (size_t)((t + 1) & 1) * HID + u, pk,
                           __ATOMIC_RELAXED, __HIP_MEMORY_SCOPE_AGENT);
      }
    }

    // Nothing below may be scheduled above the publish.
    __builtin_amdgcn_sched_barrier(0);

    // P) EARLY poll issue for tag t+1: the shadow work below now hides
    // under this set's flight time instead of delaying it.
    if (t < T_STEPS) {
      const unsigned long long* hsn =
          hbuf + (size_t)((t + 1) & 1) * HID + wslot * 256;
      A0 = PLOAD(hsn + lane);
      A1 = PLOAD(hsn + 64 + lane);
      A2 = PLOAD(hsn + 128 + lane);
      A3 = PLOAD(hsn + 192 + lane);
    }
    __builtin_amdgcn_sched_barrier(0);

    // F) y_{t-1} = out_w[u] . h_{t-1} + out_b[u]  (shadow work)
    if (t > 0) {
      float yv = 0.0f;
#pragma unroll
      for (int k = 0; k < 4; ++k) {
        yv = fmaf(O[k].x, hv[k].x, yv); yv = fmaf(O[k].y, hv[k].y, yv);
        yv = fmaf(O[k].z, hv[k].z, yv); yv = fmaf(O[k].w, hv[k].w, yv);
      }
      yv = wave_sum63(yv);
      if (lane == 63) out[(size_t)(t - 1) * OUT_DIM + u] = yv + oby;
    }

    // G) x-partials for step t+1 (shadow work; xn latency already covered)
    if (havex) {
#pragma unroll
      for (int r = 0; r < 4; ++r) {
        float s = 0.0f;
#pragma unroll
        for (int k = 0; k < 4; ++k) {
          const f32x4 wx = wxl[r * 256 + k * 64 + lane];
          s = fmaf(wx.x, xn[k].x, s); s = fmaf(wx.y, xn[k].y, s);
          s = fmaf(wx.z, xn[k].z, s); s = fmaf(wx.w, xn[k].w, s);
        }
        pp[r] = s;
      }
    }
  }
}

// ---------------------------------------------------------------------------
// Workspace layout (bytes): [0, 16K) : hbuf[2][1024] tagged u64 (memset 0)
// ---------------------------------------------------------------------------
extern "C" void kernel_launch(void* const* d_in, const int* in_sizes, int n_in,
                              void* d_out, int out_size, void* d_ws, size_t ws_size,
                              hipStream_t stream) {
  (void)in_sizes; (void)n_in; (void)out_size; (void)ws_size;

  const float* x     = (const float*)d_in[0];  // [T,1,IN]
  const float* W_w   = (const float*)d_in[1];  // [4096, 2048]
  const float* W_b   = (const float*)d_in[2];  // [4096]
  const float* out_w = (const float*)d_in[3];  // [1024, 1024]
  const float* out_b = (const float*)d_in[4];  // [1024]
  float* out = (float*)d_out;                  // [T,1,1024]

  unsigned long long* hbuf = (unsigned long long*)d_ws;
  hipMemsetAsync(d_ws, 0, 16384, stream);

  lstm_fused<<<NBLK, TPB, 0, stream>>>(W_w, x, out_w, W_b, out_b, hbuf, out);
}

// Round 4
// 11620.560 us; speedup vs baseline: 1.5083x; 1.5083x over previous
//
#include <hip/hip_runtime.h>
#include <cstdint>
#include <cstddef>

// Problem constants
#define T_STEPS 8192
#define IN_DIM  1024
#define HID     1024
#define OUT_DIM 1024
#define G4      4096   // 4*HID

// Recurrence geometry: 256 blocks x 256 threads (4 waves), 1 block/CU.
// R12 == R11 resubmit (container infra failed twice; no kernel verdict).
// R11: R10 regressed (17.5ms) -- early poll issue pre-touched about-to-be-
// written lines and the staggered spin doubled poll traffic; both inflate
// L3 coherence-point contention that the publish stores must traverse.
// REVERT spin to R9's single-set form (12.2ms).
// NEW vs R9: in R9 the x-prefetch (4 L3 loads) and the out-store were
// issued between publish and spin, and the spin's first s_waitcnt vmcnt(0)
// DRAINED them into the critical path every step (~hundreds of cycles).
// Now the x-prefetch is double-buffered across iterations: issue x[t+2] in
// the publish shadow, consume x[t+1] (issued a full step ago, already
// retired) in G. Read-only data => none of R10's coherence pollution.
#define NBLK 256
#define TPB  256
#define UPB  4    // units per block (1 per wave)

typedef __attribute__((ext_vector_type(4))) float f32x4;

#define PLOAD(p) __hip_atomic_load((p), __ATOMIC_RELAXED, __HIP_MEMORY_SCOPE_AGENT)

__device__ __forceinline__ float sigf(float x) {
  return 1.0f / (1.0f + __expf(-x));
}

template<int CTRL>
__device__ __forceinline__ float dpp_add(float v) {
  int p = __builtin_amdgcn_update_dpp(0, __float_as_int(v), CTRL, 0xf, 0xf, true);
  return v + __int_as_float(p);
}

// Full 64-lane sum, all-VALU (DPP). Result valid in LANE 63 only.
__device__ __forceinline__ float wave_sum63(float v) {
  v = dpp_add<0xB1>(v);    // quad_perm [1,0,3,2]
  v = dpp_add<0x4E>(v);    // quad_perm [2,3,0,1]
  v = dpp_add<0x141>(v);   // row_half_mirror
  v = dpp_add<0x140>(v);   // row_mirror
  v = dpp_add<0x142>(v);   // row_bcast15
  v = dpp_add<0x143>(v);   // row_bcast31
  return v;
}

// ---------------------------------------------------------------------------
// Fused persistent LSTM: tagged dataflow (no device barrier), LDS-resident
// W_h and W_x, reg-resident out_w row. hbuf: [2][1024] u64 {lo=tag, hi=h}.
// Iteration t (t = 0..T inclusive):
//   B) spin on my 256-chunk of slot t&1 for tag t (R9 single-set spin;
//      FIRST vmem of the iteration, so its vmcnt(0) drain is cheap)
//   C) deposit into lh[t&1]; raw barrier (lgkmcnt only; vmem in flight)
//   D) hv = full h_{t-1} from LDS
//   E) [t<T] gates: chain init = pp[] (x-partials), 64 FMA vs reg-pinned
//      W_h, DPP reduce -> lane 63: acts, c, h, publish tag t+1
//   -- sched_barrier: nothing below may delay the publish --
//   X) [t+2<T] issue x[t+2] prefetch into xnN (read-only; earliest vmem
//      point => ~shadow+L of flight before the next spin drains it)
//   F) [t>0] y_{t-1} = out_w[u].hv (+DPP reduce), lane 63 stores out[t-1]
//   G) [t+1<T] pp[] = partials of W_x . x_{t+1} from xnP (retired long ago)
//   R) xnP <= xnN (register rotate)
// Skew safety (unchanged from R9): every wave consumes the FULL h each step
// via its chunk + barrier; tag t+2 publish implies all waves passed poll
// t+1, so depth-2 slots never skip a tag. Publish stores are never
// vmcnt-drained in-loop; pollers enforce visibility.
// ---------------------------------------------------------------------------
__global__ __launch_bounds__(TPB, 1) void lstm_fused(
    const float* __restrict__ Ww,                 // [4096, 2048]
    const float* __restrict__ xg,                 // [T, 1024]
    const float* __restrict__ owm,                // [1024, 1024]
    const float* __restrict__ wb,                 // [4096]
    const float* __restrict__ obv,                // [1024]
    unsigned long long* __restrict__ hbuf,        // [2][1024] tagged
    float* __restrict__ out)                      // [T, 1024]
{
  __shared__ float whlds[16][HID];  // 64 KB: W_h rows m = ul*4+g
  __shared__ float wxlds[16][HID];  // 64 KB: W_x rows, same layout
  __shared__ float lh[2][HID];      // 8 KB: staged h, double-buffered

  const int tid = threadIdx.x;
  const int lane = tid & 63;
  const int wslot = tid >> 6;                 // 0..3 = unit-in-block
  const int u = blockIdx.x * UPB + wslot;     // this wave's hidden unit

  // Stage W_h and W_x rows for this block (float4, coalesced).
  {
    const float4* __restrict__ Ww4 = (const float4*)Ww;  // row stride 512 f4
    float4* wh4 = (float4*)&whlds[0][0];
    float4* wx4 = (float4*)&wxlds[0][0];
    for (int i = tid; i < 16 * 256; i += TPB) {
      const int m = i >> 8;            // 0..15
      const int e4 = i & 255;          // float4 index within row
      const int gg = m & 3;
      const int ul = m >> 2;
      const size_t row = (size_t)(gg * HID + blockIdx.x * UPB + ul) * 512;
      wh4[i] = Ww4[row + (IN_DIM / 4) + e4];   // recurrent half
      wx4[i] = Ww4[row + e4];                  // input half
    }
  }
  __syncthreads();

  const f32x4* wl4 = (const f32x4*)&whlds[wslot * 4][0];
  const f32x4* wxl = (const f32x4*)&wxlds[wslot * 4][0];

  // Hoist W_h fragments into registers for the whole loop (loop-invariant).
  f32x4 W[16];
#pragma unroll
  for (int r = 0; r < 4; ++r)
#pragma unroll
    for (int k = 0; k < 4; ++k)
      W[r * 4 + k] = wl4[r * 256 + k * 64 + lane];
#pragma unroll
  for (int i = 0; i < 16; ++i) asm volatile("" : "+v"(W[i]));

  // out_w row for this unit, pinned (16 VGPRs).
  f32x4 O[4];
  {
    const f32x4* ow4 = (const f32x4*)(owm + (size_t)u * HID);
#pragma unroll
    for (int k = 0; k < 4; ++k) O[k] = ow4[k * 64 + lane];
#pragma unroll
    for (int k = 0; k < 4; ++k) asm volatile("" : "+v"(O[k]));
  }

  const float bi = wb[u],           bf = wb[HID + u];
  const float bg = wb[2 * HID + u], bo = wb[3 * HID + u];
  const float oby = obv[u];

  // Prologue: x-partials for step 0, and xnP = x[1] for step 0's G.
  float pp[4];
  {
    const f32x4* xt4 = (const f32x4*)xg;
    f32x4 x0[4];
#pragma unroll
    for (int k = 0; k < 4; ++k) x0[k] = xt4[k * 64 + lane];
#pragma unroll
    for (int r = 0; r < 4; ++r) {
      float s = 0.0f;
#pragma unroll
      for (int k = 0; k < 4; ++k) {
        const f32x4 wx = wxl[r * 256 + k * 64 + lane];
        s = fmaf(wx.x, x0[k].x, s); s = fmaf(wx.y, x0[k].y, s);
        s = fmaf(wx.z, x0[k].z, s); s = fmaf(wx.w, x0[k].w, s);
      }
      pp[r] = s;
    }
  }
  f32x4 xnP[4];
  {
    const f32x4* xt4 = (const f32x4*)(xg + (size_t)1 * IN_DIM);
#pragma unroll
    for (int k = 0; k < 4; ++k) xnP[k] = xt4[k * 64 + lane];
  }

  float c = 0.0f;

  for (int t = 0; t <= T_STEPS; ++t) {
    // B) spin: first vmem ops of the iteration (R9 single-set form).
    const unsigned long long* hs = hbuf + (size_t)(t & 1) * HID + wslot * 256;
    const unsigned want = (unsigned)t;
    unsigned long long p0, p1, p2, p3;
    for (;;) {
      p0 = PLOAD(hs + lane);
      p1 = PLOAD(hs + 64 + lane);
      p2 = PLOAD(hs + 128 + lane);
      p3 = PLOAD(hs + 192 + lane);
      bool ok = ((unsigned)p0 == want) & ((unsigned)p1 == want) &
                ((unsigned)p2 == want) & ((unsigned)p3 == want);
      if (__all((int)ok)) break;
    }
    {
      float* dst = &lh[t & 1][wslot * 256];
      dst[lane]       = __uint_as_float((unsigned)(p0 >> 32));
      dst[64 + lane]  = __uint_as_float((unsigned)(p1 >> 32));
      dst[128 + lane] = __uint_as_float((unsigned)(p2 >> 32));
      dst[192 + lane] = __uint_as_float((unsigned)(p3 >> 32));
    }

    // C) raw barrier: drain LDS ops only; global loads/stores stay in flight
    asm volatile("s_waitcnt lgkmcnt(0)\n\ts_barrier" ::: "memory");

    // D) full h_{t-1} from LDS
    const f32x4* lhp = (const f32x4*)&lh[t & 1][0];
    f32x4 hv[4];
#pragma unroll
    for (int k = 0; k < 4; ++k) hv[k] = lhp[k * 64 + lane];

    // E) gates -> h_t -> publish (critical path; lane 63 is the publisher)
    if (t < T_STEPS) {
      float a[4];
#pragma unroll
      for (int r = 0; r < 4; ++r) {
        float s = pp[r];   // x-partial initializes the chain (summed by tree)
#pragma unroll
        for (int k = 0; k < 4; ++k) {
          s = fmaf(W[r*4+k].x, hv[k].x, s); s = fmaf(W[r*4+k].y, hv[k].y, s);
          s = fmaf(W[r*4+k].z, hv[k].z, s); s = fmaf(W[r*4+k].w, hv[k].w, s);
        }
        a[r] = wave_sum63(s);
      }
      // Only lane 63 holds real sums; other lanes compute garbage harmlessly.
      const float gi = a[0] + bi, gf = a[1] + bf, gc = a[2] + bg, go = a[3] + bo;
      const float si = sigf(gi), sf = sigf(gf), so = sigf(go);
      const float tg = fmaf(2.0f, sigf(2.0f * gc), -1.0f);   // tanh
      c = fmaf(sf, c, si * tg);
      const float h = so * fmaf(2.0f, sigf(2.0f * c), -1.0f);
      if (lane == 63) {
        const unsigned long long pk =
            ((unsigned long long)__float_as_uint(h) << 32) | (unsigned)(t + 1);
        __hip_atomic_store(hbuf + (size_t)((t + 1) & 1) * HID + u, pk,
                           __ATOMIC_RELAXED, __HIP_MEMORY_SCOPE_AGENT);
      }
    }

    // Nothing below may be scheduled above the publish.
    __builtin_amdgcn_sched_barrier(0);

    // X) x[t+2] prefetch: earliest vmem point after publish. Read-only
    // data -- no coherence pollution. Gets ~shadow + poll-L of flight
    // before the next spin's vmcnt(0) can drain it.
    f32x4 xnN[4];
    const bool pf = (t + 2 < T_STEPS);
    if (pf) {
      const f32x4* xt4 = (const f32x4*)(xg + (size_t)(t + 2) * IN_DIM);
#pragma unroll
      for (int k = 0; k < 4; ++k) xnN[k] = xt4[k * 64 + lane];
    }

    // F) y_{t-1} = out_w[u] . h_{t-1} + out_b[u]; store also has a full
    // shadow+spin to retire before the next drain.
    if (t > 0) {
      float yv = 0.0f;
#pragma unroll
      for (int k = 0; k < 4; ++k) {
        yv = fmaf(O[k].x, hv[k].x, yv); yv = fmaf(O[k].y, hv[k].y, yv);
        yv = fmaf(O[k].z, hv[k].z, yv); yv = fmaf(O[k].w, hv[k].w, yv);
      }
      yv = wave_sum63(yv);
      if (lane == 63) out[(size_t)(t - 1) * OUT_DIM + u] = yv + oby;
    }
    __builtin_amdgcn_sched_barrier(0);

    // G) x-partials for step t+1 from xnP (issued a full step ago --
    // retired by this iteration's spin drain; never stalls).
    if (t + 1 < T_STEPS) {
#pragma unroll
      for (int r = 0; r < 4; ++r) {
        float s = 0.0f;
#pragma unroll
        for (int k = 0; k < 4; ++k) {
          const f32x4 wx = wxl[r * 256 + k * 64 + lane];
          s = fmaf(wx.x, xnP[k].x, s); s = fmaf(wx.y, xnP[k].y, s);
          s = fmaf(wx.z, xnP[k].z, s); s = fmaf(wx.w, xnP[k].w, s);
        }
        pp[r] = s;
      }
    }

    // R) rotate the x double-buffer (16 v_mov in the shadow).
    if (pf) {
#pragma unroll
      for (int k = 0; k < 4; ++k) xnP[k] = xnN[k];
    }
  }
}

// ---------------------------------------------------------------------------
// Workspace layout (bytes): [0, 16K) : hbuf[2][1024] tagged u64 (memset 0)
// ---------------------------------------------------------------------------
extern "C" void kernel_launch(void* const* d_in, const int* in_sizes, int n_in,
                              void* d_out, int out_size, void* d_ws, size_t ws_size,
                              hipStream_t stream) {
  (void)in_sizes; (void)n_in; (void)out_size; (void)ws_size;

  const float* x     = (const float*)d_in[0];  // [T,1,IN]
  const float* W_w   = (const float*)d_in[1];  // [4096, 2048]
  const float* W_b   = (const float*)d_in[2];  // [4096]
  const float* out_w = (const float*)d_in[3];  // [1024, 1024]
  const float* out_b = (const float*)d_in[4];  // [1024]
  float* out = (float*)d_out;                  // [T,1,1024]

  unsigned long long* hbuf = (unsigned long long*)d_ws;
  hipMemsetAsync(d_ws, 0, 16384, stream);

  lstm_fused<<<NBLK, TPB, 0, stream>>>(W_w, x, out_w, W_b, out_b, hbuf, out);
}